// Round 10
// baseline (318.892 us; speedup 1.0000x reference)
//
#include <hip/hip_runtime.h>

typedef unsigned short u16;
typedef unsigned int u32;
typedef short short8 __attribute__((ext_vector_type(8)));
typedef float f32x4 __attribute__((ext_vector_type(4)));

#define LN_EPS 1e-3f
#define PI2 6.28318530717958647692f
#define AS1 __attribute__((address_space(1)))
#define AS3 __attribute__((address_space(3)))

__device__ __forceinline__ u16 f2bf(float f) {
  u32 u = __float_as_uint(f);
  u += 0x7fffu + ((u >> 16) & 1u);
  return (u16)(u >> 16);
}
__device__ __forceinline__ float bf2f(u16 h) {
  return __uint_as_float(((u32)h) << 16);
}

// ------- weight transpose + bf16: W[R][C] f32 -> Wt[C][R] bf16, 32x32 LDS tiles ----
__global__ __launch_bounds__(256) void prep_w(const float* __restrict__ W,
                                              u16* __restrict__ Wt, int R, int C) {
  __shared__ float tile[32][33];
  const int ct = C >> 5;
  int bc = blockIdx.x % ct;
  int br = blockIdx.x / ct;
  int tx = threadIdx.x & 31, ty = threadIdx.x >> 5;
  int r0 = br << 5, c0 = bc << 5;
#pragma unroll
  for (int i = 0; i < 32; i += 8)
    tile[ty + i][tx] = W[(size_t)(r0 + ty + i) * C + c0 + tx];
  __syncthreads();
#pragma unroll
  for (int i = 0; i < 32; i += 8)
    Wt[(size_t)(c0 + ty + i) * R + r0 + tx] = f2bf(tile[tx][ty + i]);
}

// ------- x[b][s][d] f32 -> xt[b][d][s] bf16 (tiled 32x32) ----------------
__global__ __launch_bounds__(256) void transpose_x(const float* __restrict__ x,
                                                   u16* __restrict__ xt) {
  __shared__ float tile[32][33];
  int blk = blockIdx.x;
  int b = blk >> 12;
  int rem = blk & 4095;
  int st = rem >> 4;   // s-tile 0..255
  int dt = rem & 15;   // d-tile 0..15
  int tx = threadIdx.x & 31, ty = threadIdx.x >> 5;
  int s0 = st << 5, d0 = dt << 5;
#pragma unroll
  for (int i = 0; i < 32; i += 8)
    tile[ty + i][tx] = x[(((size_t)(b << 13) + s0 + ty + i) << 9) + d0 + tx];
  __syncthreads();
#pragma unroll
  for (int i = 0; i < 32; i += 8)
    xt[(((size_t)(b << 9) + d0 + ty + i) << 13) + s0 + tx] = f2bf(tile[tx][ty + i]);
}

// ---------------- S-axis FFT (8192-pt DIF, register-blocked radix-16) --------------
// bf16 in / bf16 out (internals f32). Hermitian: only k in [0,4096] stored.
__device__ __constant__ float C16r[8] = {1.f, 0.92387953f, 0.70710678f, 0.38268343f,
                                         0.f, -0.38268343f, -0.70710678f, -0.92387953f};
__device__ __constant__ float C16i[8] = {0.f, -0.38268343f, -0.70710678f, -0.92387953f,
                                         -1.f, -0.92387953f, -0.70710678f, -0.38268343f};
__device__ __constant__ float C8r[4] = {1.f, 0.70710678f, 0.f, -0.70710678f};
__device__ __constant__ float C8i[4] = {0.f, -0.70710678f, -1.f, -0.70710678f};
__device__ __constant__ float C4r[2] = {1.f, 0.f};
__device__ __constant__ float C4i[2] = {0.f, -1.f};
__device__ __constant__ float C32r[16] = {
    1.f, 0.98078528f, 0.92387953f, 0.83146961f, 0.70710678f, 0.55557023f,
    0.38268343f, 0.19509032f, 0.f, -0.19509032f, -0.38268343f, -0.55557023f,
    -0.70710678f, -0.83146961f, -0.92387953f, -0.98078528f};
__device__ __constant__ float C32i[16] = {
    0.f, -0.19509032f, -0.38268343f, -0.55557023f, -0.70710678f, -0.83146961f,
    -0.92387953f, -0.98078528f, -1.f, -0.98078528f, -0.92387953f, -0.83146961f,
    -0.70710678f, -0.55557023f, -0.38268343f, -0.19509032f};
__device__ __constant__ int REV4[16] = {0, 8, 4, 12, 2, 10, 6, 14,
                                        1, 9, 5, 13, 3, 11, 7, 15};

__device__ __forceinline__ constexpr int rev4c(int v) {
  return ((v & 1) << 3) | ((v & 2) << 1) | ((v & 4) >> 1) | ((v & 8) >> 3);
}

#define BFLY(ar, ai, br, bi, wr, wi)                 \
  {                                                  \
    float dr_ = (ar) - (br), di_ = (ai) - (bi);      \
    (ar) += (br);                                    \
    (ai) += (bi);                                    \
    (br) = dr_ * (wr)-di_ * (wi);                    \
    (bi) = dr_ * (wi) + di_ * (wr);                  \
  }

__global__ __launch_bounds__(512) void fft_s(u16* __restrict__ X, u16* __restrict__ Xim) {
  __shared__ float zr[8448], zi[8448];      // padded: addr(i) = i + (i>>5)
  const int t = threadIdx.x;
  const int b = blockIdx.x >> 8;
  const int d0 = (blockIdx.x & 255) << 1;
  u16* r0 = X + (((size_t)(b << 9) + d0) << 13);
  u16* r1 = r0 + 8192;

  float xr[16], xi[16];
#pragma unroll
  for (int e = 0; e < 16; ++e) {            // coalesced loads, idx = t + 512e
    xr[e] = bf2f(r0[t + (e << 9)]);
    xi[e] = bf2f(r1[t + (e << 9)]);
  }

  // ---- pass A: strides 4096,2048,1024,512 in-register ----
  float c1, s1;
  sincosf(-PI2 * (float)t * (1.0f / 8192.0f), &s1, &c1);
  float c2 = c1 * c1 - s1 * s1, s2 = 2.f * c1 * s1;
  float c4 = c2 * c2 - s2 * s2, s4 = 2.f * c2 * s2;
  float c8 = c4 * c4 - s4 * s4, s8 = 2.f * c4 * s4;
#pragma unroll
  for (int e = 0; e < 8; ++e) {             // m=8192
    float wr = c1 * C16r[e] - s1 * C16i[e];
    float wi = c1 * C16i[e] + s1 * C16r[e];
    BFLY(xr[e], xi[e], xr[e + 8], xi[e + 8], wr, wi);
  }
#pragma unroll
  for (int e = 0; e < 16; ++e) {            // m=4096
    if ((e & 4) == 0) {
      int eb = e & 3;
      float wr = c2 * C8r[eb] - s2 * C8i[eb];
      float wi = c2 * C8i[eb] + s2 * C8r[eb];
      BFLY(xr[e], xi[e], xr[e + 4], xi[e + 4], wr, wi);
    }
  }
#pragma unroll
  for (int e = 0; e < 16; ++e) {            // m=2048
    if (((e >> 1) & 1) == 0) {
      int eb = e & 1;
      float wr = c4 * C4r[eb] - s4 * C4i[eb];
      float wi = c4 * C4i[eb] + s4 * C4r[eb];
      BFLY(xr[e], xi[e], xr[e + 2], xi[e + 2], wr, wi);
    }
  }
#pragma unroll
  for (int e = 0; e < 16; e += 2) {         // m=1024
    BFLY(xr[e], xi[e], xr[e + 1], xi[e + 1], c8, s8);
  }

  // ---- exchange A->B ----
#pragma unroll
  for (int e = 0; e < 16; ++e) {
    int idx = t + (e << 9);
    int a = idx + (idx >> 5);
    zr[a] = xr[e];
    zi[a] = xi[e];
  }
  __syncthreads();
  {
    const int f = t >> 5, l = t & 31;
#pragma unroll
    for (int e = 0; e < 16; ++e) {
      int idx = (f << 9) + (e << 5) + l;
      int a = idx + (idx >> 5);
      xr[e] = zr[a];
      xi[e] = zi[a];
    }
    // ---- pass B: strides 256,128,64,32 ----
    float bc1, bs1;
    sincosf(-PI2 * (float)l * (1.0f / 512.0f), &bs1, &bc1);
    float bc2 = bc1 * bc1 - bs1 * bs1, bs2 = 2.f * bc1 * bs1;
    float bc4 = bc2 * bc2 - bs2 * bs2, bs4 = 2.f * bc2 * bs2;
    float bc8 = bc4 * bc4 - bs4 * bs4, bs8 = 2.f * bc4 * bs4;
#pragma unroll
    for (int e = 0; e < 8; ++e) {           // m=512
      float wr = bc1 * C16r[e] - bs1 * C16i[e];
      float wi = bc1 * C16i[e] + bs1 * C16r[e];
      BFLY(xr[e], xi[e], xr[e + 8], xi[e + 8], wr, wi);
    }
#pragma unroll
    for (int e = 0; e < 16; ++e) {          // m=256
      if (((e >> 2) & 1) == 0) {
        int eb = e & 3;
        float wr = bc2 * C8r[eb] - bs2 * C8i[eb];
        float wi = bc2 * C8i[eb] + bs2 * C8r[eb];
        BFLY(xr[e], xi[e], xr[e + 4], xi[e + 4], wr, wi);
      }
    }
#pragma unroll
    for (int e = 0; e < 16; ++e) {          // m=128
      if (((e >> 1) & 1) == 0) {
        int eb = e & 1;
        float wr = bc4 * C4r[eb] - bs4 * C4i[eb];
        float wi = bc4 * C4i[eb] + bs4 * C4r[eb];
        BFLY(xr[e], xi[e], xr[e + 2], xi[e + 2], wr, wi);
      }
    }
#pragma unroll
    for (int e = 0; e < 16; e += 2) {       // m=64
      BFLY(xr[e], xi[e], xr[e + 1], xi[e + 1], bc8, bs8);
    }
    // ---- exchange B->C ----
    __syncthreads();
#pragma unroll
    for (int e = 0; e < 16; ++e) {
      int idx = (f << 9) + (e << 5) + l;
      int a = idx + (idx >> 5);
      zr[a] = xr[e];
      zi[a] = xi[e];
    }
  }
  __syncthreads();
#pragma unroll
  for (int j = 0; j < 16; ++j) {
    int idx = (t << 4) + j;
    int a = idx + (idx >> 5);
    xr[j] = zr[a];
    xi[j] = zi[a];
  }

  // ---- pass C: stride 16 via shfl, then 8,4,2,1 ----
  {
    const int odd = t & 1;
#pragma unroll
    for (int j = 0; j < 16; ++j) {          // m=32
      float pr = __shfl_xor(xr[j], 1);
      float pi = __shfl_xor(xi[j], 1);
      if (!odd) {
        xr[j] += pr;
        xi[j] += pi;
      } else {
        float dr = pr - xr[j], di = pi - xi[j];
        xr[j] = dr * C32r[j] - di * C32i[j];
        xi[j] = dr * C32i[j] + di * C32r[j];
      }
    }
#pragma unroll
    for (int j = 0; j < 8; ++j) {           // m=16
      BFLY(xr[j], xi[j], xr[j + 8], xi[j + 8], C16r[j], C16i[j]);
    }
#pragma unroll
    for (int j = 0; j < 16; ++j) {          // m=8
      if (((j >> 2) & 1) == 0) {
        BFLY(xr[j], xi[j], xr[j + 4], xi[j + 4], C8r[j & 3], C8i[j & 3]);
      }
    }
#pragma unroll
    for (int j = 0; j < 16; ++j) {          // m=4
      if (((j >> 1) & 1) == 0) {
        BFLY(xr[j], xi[j], xr[j + 2], xi[j + 2], C4r[j & 1], C4i[j & 1]);
      }
    }
#pragma unroll
    for (int j = 0; j < 16; j += 2) {       // m=2
      BFLY(xr[j], xi[j], xr[j + 1], xi[j + 1], 1.0f, 0.0f);
    }
  }

  // ---- bit-reversal scatter ----
  __syncthreads();
  {
    const int rt = __brev((u32)t) >> 23;    // 9-bit reverse
#pragma unroll
    for (int j = 0; j < 16; ++j) {
      int k = (REV4[j] << 9) | rt;
      int a = k + (k >> 5);
      zr[a] = xr[j];
      zi[a] = xi[j];
    }
  }
  __syncthreads();

  // ---- unpack two real FFTs; store only k in [0,4096] (Hermitian), bf16 ----
  u16* i0 = Xim + (((size_t)(b << 9) + d0) << 13);
  u16* i1 = i0 + 8192;
#pragma unroll
  for (int e = 0; e < 8; ++e) {
    int k = t + (e << 9);                   // 0..4095
    int nk = (8192 - k) & 8191;
    int ka = k + (k >> 5), na = nk + (nk >> 5);
    float zrk = zr[ka], zik = zi[ka], zrn = zr[na], zin = zi[na];
    r0[k] = f2bf(0.5f * (zrk + zrn));
    i0[k] = f2bf(0.5f * (zik - zin));
    r1[k] = f2bf(0.5f * (zik + zin));
    i1[k] = f2bf(0.5f * (zrn - zrk));
  }
  if (t == 0) {                             // k = 4096 (Nyquist, self-mirror)
    const int ka = 4096 + (4096 >> 5);
    r0[4096] = f2bf(zr[ka]);
    i0[4096] = 0;
    r1[4096] = f2bf(zi[ka]);
    i1[4096] = 0;
  }
}

// ------- D-axis FFT (512-pt, register-blocked) + residual + LN1, Hermitian dual ----
// bf16 spectral inputs; x residual f32. Grid: 4 batches x 257 k-tiles of 16 rows.
__global__ __launch_bounds__(256) void fft_d_ln(
    const u16* __restrict__ Xre, const u16* __restrict__ Xim,
    const float* __restrict__ x, const float* __restrict__ g1,
    const float* __restrict__ be1, u16* __restrict__ proj) {
  __shared__ float buf[16 * 528];           // 33792 B, one buffer for all phases
  const int tid = threadIdx.x;
  const int b = blockIdx.x / 257;
  const int kt = blockIdx.x - b * 257;
  const int s0 = kt << 4;                   // 0, 16, ..., 4096
  const int row = tid >> 4, t = tid & 15;   // compute roles
  const int so = tid & 15, dd = tid >> 4;   // staging roles

  float xr[32], xi[32];

#pragma unroll
  for (int it = 0; it < 32; ++it) {
    int d = dd + (it << 4);
    buf[so * 516 + d] = bf2f(Xre[(((size_t)(b << 9) + d) << 13) + s0 + so]);
  }
  __syncthreads();
#pragma unroll
  for (int e = 0; e < 32; ++e) xr[e] = buf[row * 516 + t + (e << 4)];
  __syncthreads();
#pragma unroll
  for (int it = 0; it < 32; ++it) {
    int d = dd + (it << 4);
    buf[so * 516 + d] = bf2f(Xim[(((size_t)(b << 9) + d) << 13) + s0 + so]);
  }
  __syncthreads();
#pragma unroll
  for (int e = 0; e < 32; ++e) xi[e] = buf[row * 516 + t + (e << 4)];
  __syncthreads();

  // ---- 5 DIF stages in-register (strides 256,128,64,32,16) ----
  float c1, s1;
  sincosf(-PI2 * (float)t * (1.0f / 512.0f), &s1, &c1);
  float c2 = c1 * c1 - s1 * s1, s2 = 2.f * c1 * s1;    // W256^t
  float c4 = c2 * c2 - s2 * s2, s4 = 2.f * c2 * s2;    // W128^t
  float c8 = c4 * c4 - s4 * s4, s8 = 2.f * c4 * s4;    // W64^t
  float c16 = c8 * c8 - s8 * s8, s16 = 2.f * c8 * s8;  // W32^t
#pragma unroll
  for (int e = 0; e < 16; ++e) {            // half=256
    float wr = c1 * C32r[e] - s1 * C32i[e];
    float wi = c1 * C32i[e] + s1 * C32r[e];
    BFLY(xr[e], xi[e], xr[e + 16], xi[e + 16], wr, wi);
  }
#pragma unroll
  for (int e = 0; e < 32; ++e) {            // half=128
    if ((e & 8) == 0) {
      int eb = e & 7;
      float wr = c2 * C16r[eb] - s2 * C16i[eb];
      float wi = c2 * C16i[eb] + s2 * C16r[eb];
      BFLY(xr[e], xi[e], xr[e + 8], xi[e + 8], wr, wi);
    }
  }
#pragma unroll
  for (int e = 0; e < 32; ++e) {            // half=64
    if ((e & 4) == 0) {
      int eb = e & 3;
      float wr = c4 * C8r[eb] - s4 * C8i[eb];
      float wi = c4 * C8i[eb] + s4 * C8r[eb];
      BFLY(xr[e], xi[e], xr[e + 4], xi[e + 4], wr, wi);
    }
  }
#pragma unroll
  for (int e = 0; e < 32; ++e) {            // half=32
    if ((e & 2) == 0) {
      int eb = e & 1;
      float wr = c8 * C4r[eb] - s8 * C4i[eb];
      float wi = c8 * C4i[eb] + s8 * C4r[eb];
      BFLY(xr[e], xi[e], xr[e + 2], xi[e + 2], wr, wi);
    }
  }
#pragma unroll
  for (int e = 0; e < 32; e += 2) {         // half=16
    BFLY(xr[e], xi[e], xr[e + 1], xi[e + 1], c16, s16);
  }

  // ---- exchange ----
#pragma unroll
  for (int e = 0; e < 32; ++e) {
    int p = (e << 4) + t;
    buf[row * 528 + p + (p >> 5)] = xr[e];
  }
  __syncthreads();
#pragma unroll
  for (int j = 0; j < 32; ++j) xr[j] = buf[row * 528 + 33 * t + j];
  __syncthreads();
#pragma unroll
  for (int e = 0; e < 32; ++e) {
    int p = (e << 4) + t;
    buf[row * 528 + p + (p >> 5)] = xi[e];
  }
  __syncthreads();
#pragma unroll
  for (int j = 0; j < 32; ++j) xi[j] = buf[row * 528 + 33 * t + j];
  __syncthreads();

  // ---- two 16-pt DIF FFTs in-register ----
#pragma unroll
  for (int o = 0; o < 32; o += 16) {
#pragma unroll
    for (int j = 0; j < 8; ++j)             // half=8
      BFLY(xr[o + j], xi[o + j], xr[o + j + 8], xi[o + j + 8], C16r[j], C16i[j]);
#pragma unroll
    for (int j = 0; j < 16; ++j)            // half=4
      if ((j & 4) == 0)
        BFLY(xr[o + j], xi[o + j], xr[o + j + 4], xi[o + j + 4], C8r[j & 3], C8i[j & 3]);
#pragma unroll
    for (int j = 0; j < 16; ++j)            // half=2
      if ((j & 2) == 0)
        BFLY(xr[o + j], xi[o + j], xr[o + j + 2], xi[o + j + 2], C4r[j & 1], C4i[j & 1]);
#pragma unroll
    for (int j = 0; j < 16; j += 2)         // half=1
      BFLY(xr[o + j], xi[o + j], xr[o + j + 1], xi[o + j + 1], 1.0f, 0.0f);
  }

  // ---- scatter Re at bit-reversed k ----
  {
    const int rt4 = __brev((u32)t) >> 28;
#pragma unroll
    for (int j = 0; j < 16; ++j) {
      const int rj = rev4c(j);
      buf[row * 528 + 33 * rj + rt4] = xr[j];
      buf[row * 528 + 33 * rj + 16 + rt4] = xr[16 + j];
    }
  }
  __syncthreads();

  const int k = s0 + row;
  // ---- main row k: residual add + LN over D=512, write if k <= 4096 ----
  {
    const float* xrow = x + (((size_t)(b << 13) + k) << 9);
    float v[32];
    float sum = 0.f, sum2 = 0.f;
#pragma unroll
    for (int m = 0; m < 32; ++m) {
      int d = t + (m << 4);
      float val = buf[row * 528 + d + (d >> 5)] + xrow[d];
      v[m] = val;
      sum += val;
      sum2 += val * val;
    }
#pragma unroll
    for (int m = 1; m < 16; m <<= 1) {
      sum += __shfl_xor(sum, m, 16);
      sum2 += __shfl_xor(sum2, m, 16);
    }
    float mean = sum * (1.0f / 512.0f);
    float var = sum2 * (1.0f / 512.0f) - mean * mean;
    float scl = 1.0f / sqrtf(var + LN_EPS);
    if (k <= 4096) {
      u16* prow = proj + (((size_t)(b << 13) + k) << 9);
#pragma unroll
      for (int m = 0; m < 32; ++m) {
        int d = t + (m << 4);
        prow[d] = f2bf((v[m] - mean) * scl * g1[d] + be1[d]);
      }
    }
  }
  // ---- mirror row 8192-k: Re[d] = buf_re[(512-d)&511], for k in [1,4095] ----
  if (k >= 1 && k <= 4095) {
    const int sm = 8192 - k;
    const float* xrow = x + (((size_t)(b << 13) + sm) << 9);
    float v[32];
    float sum = 0.f, sum2 = 0.f;
#pragma unroll
    for (int m = 0; m < 32; ++m) {
      int d = t + (m << 4);
      int dm = (512 - d) & 511;
      float val = buf[row * 528 + dm + (dm >> 5)] + xrow[d];
      v[m] = val;
      sum += val;
      sum2 += val * val;
    }
#pragma unroll
    for (int m = 1; m < 16; m <<= 1) {
      sum += __shfl_xor(sum, m, 16);
      sum2 += __shfl_xor(sum2, m, 16);
    }
    float mean = sum * (1.0f / 512.0f);
    float var = sum2 * (1.0f / 512.0f) - mean * mean;
    float scl = 1.0f / sqrtf(var + LN_EPS);
    u16* prow = proj + (((size_t)(b << 13) + sm) << 9);
#pragma unroll
    for (int m = 0; m < 32; ++m) {
      int d = t + (m << 4);
      prow[d] = f2bf((v[m] - mean) * scl * g1[d] + be1[d]);
    }
  }
}

// ------- GEMM1 (K=512): barrier-free. A[64x512] in LDS once; B from L2 via regs ----
// Tile 64M x 256N, 4 waves (1m x 4n), 64 KB LDS -> 2 blocks/CU. Zero barriers in the
// K loop: after the single A-stage sync, all LDS is read-only; B frags are b128
// global loads (w1t is 2 MB, L2-resident per XCD). Accumulation order identical to
// the previous gemm_bt (K chunks of 32 in order) -> bit-identical output.
__global__ __launch_bounds__(256, 2) void gemm_k512(
    const u16* __restrict__ A, const u16* __restrict__ Bt,
    const float* __restrict__ bias, u16* __restrict__ Cout, int N) {
  const int tid = threadIdx.x;
  const int lane = tid & 63;
  const int wave = tid >> 6;                 // 0..3 = wn
  const int llo = lane & 15, lhi = lane >> 4;

  const int nwg = gridDim.x;                 // 4096, %8==0
  const int q = nwg >> 3;
  const int b2 = ((int)blockIdx.x & 7) * q + ((int)blockIdx.x >> 3);  // XCD chunk
  const int tn = b2 & 7;                     // n fast: A panel stays L2-hot
  const int tm = b2 >> 3;
  const int m0 = tm << 6, n0 = tn << 8;

  __shared__ short8 smem[4096];              // 64 KB: A[64][512] bf16, XOR-swizzled
  char* ldsA = (char*)smem;

  // ---- stage A panel (full K=512) once; 16 issues x 256thr x 16B ----
#pragma unroll
  for (int i = 0; i < 16; ++i) {
    const int r8 = (((i & 1) << 2) | (tid >> 6)) & 7;   // (row & 7)
    const u16* g = A + (size_t)(m0 + (i << 2) + (tid >> 6)) * 512 +
                   (((tid & 63) ^ r8) << 3);            // inverse-swizzled source k
    __builtin_amdgcn_global_load_lds((const AS1 void*)g,
                                     (AS3 void*)(ldsA + (i << 12) + tid * 16), 16, 0, 0);
  }
  __syncthreads();                           // only barrier in the kernel

  f32x4 acc[4][4] = {};
  const int swz = (llo & 7) << 4;            // read-side XOR (row&7 == llo&7)
  const u16* bp0 = Bt + (size_t)(n0 + (wave << 6) + llo) * 512 + (lhi << 3);

#define LOADB(bb, s)                                                     \
  {                                                                      \
    _Pragma("unroll") for (int nt = 0; nt < 4; ++nt)                     \
        bb[nt] = *(const short8*)(bp0 + (size_t)nt * 8192 + ((s) << 5)); \
  }
#define COMPUTE(bb, s)                                                              \
  {                                                                                 \
    short8 af[4];                                                                   \
    _Pragma("unroll") for (int mt = 0; mt < 4; ++mt)                                \
        af[mt] = *(const short8*)(ldsA + (((mt << 4) + llo) << 10) +                \
                                  ((((s) << 6) + (lhi << 4)) ^ swz));               \
    _Pragma("unroll") for (int mt = 0; mt < 4; ++mt)                                \
        _Pragma("unroll") for (int nt = 0; nt < 4; ++nt)                            \
            acc[mt][nt] = __builtin_amdgcn_mfma_f32_16x16x32_bf16(af[mt], bb[nt],   \
                                                                  acc[mt][nt], 0, 0, 0); \
  }

  short8 b0[4], b1[4];
  LOADB(b0, 0);
  LOADB(b1, 1);
#pragma unroll
  for (int s2 = 0; s2 < 8; ++s2) {           // 16 K-steps of 32, 2 per iter
    COMPUTE(b0, 2 * s2);
    if (s2 < 7) LOADB(b0, 2 * s2 + 2);       // refill 2 steps ahead
    COMPUTE(b1, 2 * s2 + 1);
    if (s2 < 7) LOADB(b1, 2 * s2 + 3);
  }
#undef LOADB
#undef COMPUTE

  // ---- epilogue: bias + ReLU, bf16 store (C/D map col=llo, row=lhi*4+j) ----
#pragma unroll
  for (int nt = 0; nt < 4; ++nt) {
    const int col = n0 + (wave << 6) + (nt << 4) + llo;
    const float bv = bias[col];
#pragma unroll
    for (int mt = 0; mt < 4; ++mt) {
      const int rbase = m0 + (mt << 4) + (lhi << 2);
#pragma unroll
      for (int j = 0; j < 4; ++j) {
        float v = fmaxf(acc[mt][nt][j] + bv, 0.0f);
        Cout[(size_t)(rbase + j) * N + col] = f2bf(v);
      }
    }
  }
}

// ---------------- GEMM 256x256, BK=64, 8 waves, 8-phase counted-vmcnt pipeline -----
// OMODE: 1 = bf16 store; 2 = residual RMW in-place on bf16 Cout (y = C + acc + bias)
template <bool RELU, int OMODE, int GH>
__global__ __launch_bounds__(512, 2) void gemm256(
    const u16* __restrict__ A, const u16* __restrict__ Bt,
    const float* __restrict__ bias, void* __restrict__ Cout,
    int M, int N, int K) {
  const int tid = threadIdx.x;
  const int lane = tid & 63;
  const int wave = tid >> 6;                 // 0..7
  const int wm = wave >> 2;                  // 0..1 (M half)
  const int wn = wave & 3;                   // 0..3 (N quarter)
  const int llo = lane & 15, lhi = lane >> 4;

  const int nwg = gridDim.x;                 // % 8 == 0 and % (GH*NT) == 0
  const int q = nwg >> 3;
  const int b2 = ((int)blockIdx.x & 7) * q + ((int)blockIdx.x >> 3);  // XCD chunk
  const int NT = N >> 8;
  const int GSZ = GH * NT;
  const int grp = b2 / GSZ;
  const int rr = b2 - grp * GSZ;
  const int tn = rr / GH;
  const int tm = grp * GH + (rr - tn * GH);
  const int m0 = tm << 8, n0 = tn << 8;

  __shared__ short8 smem[8192];              // 128 KB
  char* ldsA = (char*)&smem[0];              // [slot<<15][half<<14][row*128]
  char* ldsB = ldsA + 65536;

  f32x4 acc[8][4] = {};

  const int trow = tid >> 3;                                   // 0..63
  const int ksw = ((tid & 7) ^ (trow & 7)) << 3;               // presw src k (elems)
  const int swz = (llo & 7) << 4;                              // read-side XOR
  const int cb0 = (lhi << 4) ^ swz;                            // kk=0 col; kk=1: ^64
  const char* Ab0 = ldsA + wm * 16384 + llo * 128;
  const char* Bb0 = ldsB + (wn >> 1) * 16384 + (((wn & 1) << 6) + llo) * 128;

#define GLDS(g_, d_) __builtin_amdgcn_global_load_lds((const AS1 void*)(g_), (AS3 void*)(d_), 16, 0, 0)
#define STAGE_A(kt, hf) {                                                        \
    const u16* g_ = A + (size_t)(m0 + ((hf) << 7) + trow) * K + ((kt) << 6) + ksw; \
    char* d_ = ldsA + (((kt)&1) << 15) + ((hf) << 14) + tid * 16;                \
    GLDS(g_, d_); GLDS(g_ + ((size_t)64) * K, d_ + 8192); }
#define STAGE_B(kt, hf) {                                                        \
    const u16* g_ = Bt + (size_t)(n0 + ((hf) << 7) + trow) * K + ((kt) << 6) + ksw; \
    char* d_ = ldsB + (((kt)&1) << 15) + ((hf) << 14) + tid * 16;                \
    GLDS(g_, d_); GLDS(g_ + ((size_t)64) * K, d_ + 8192); }
#define BAR() { __builtin_amdgcn_sched_barrier(0); __builtin_amdgcn_s_barrier(); \
                __builtin_amdgcn_sched_barrier(0); }
#define VMW(n_) { asm volatile("s_waitcnt vmcnt(" #n_ ")" ::: "memory"); }

  const int KT = K >> 6;
  // prologue: slot0 <- kt0 (A+B), B slot1 <- kt1; A slot1 staged at P1 of iter 0
  STAGE_A(0, 0); STAGE_A(0, 1); STAGE_B(0, 0); STAGE_B(0, 1);
  STAGE_B(1, 0); STAGE_B(1, 1);
  VMW(0);
  BAR();

  for (int t0 = 0; t0 < KT; t0 += 2) {
    const bool pf = (t0 + 2 < KT);
#pragma unroll
    for (int s = 0; s < 2; ++s) {            // s=0: phases 1-4 (kt=t0); s=1: 5-8
      const char* Abase = Ab0 + (s << 15);
      const char* Bbase = Bb0 + (s << 15);
      short8 bfr[4][2];
      // ---- phase q=0: B full (8) + A fm0,1 (4); stage A of other slot ----
      {
#pragma unroll
        for (int fn = 0; fn < 4; ++fn) {
          bfr[fn][0] = *(const short8*)(Bbase + fn * 2048 + cb0);
          bfr[fn][1] = *(const short8*)(Bbase + fn * 2048 + (cb0 ^ 64));
        }
        short8 af[2][2];
#pragma unroll
        for (int i = 0; i < 2; ++i) {
          af[i][0] = *(const short8*)(Abase + i * 2048 + cb0);
          af[i][1] = *(const short8*)(Abase + i * 2048 + (cb0 ^ 64));
        }
        if (s == 0) {
          STAGE_A(t0 + 1, 0); STAGE_A(t0 + 1, 1);
        } else if (pf) {
          STAGE_A(t0 + 2, 0); STAGE_A(t0 + 2, 1);
        }
        BAR();
        __builtin_amdgcn_s_setprio(1);
#pragma unroll
        for (int i = 0; i < 2; ++i)
#pragma unroll
          for (int fn = 0; fn < 4; ++fn)
#pragma unroll
            for (int kk = 0; kk < 2; ++kk)
              acc[i][fn] = __builtin_amdgcn_mfma_f32_16x16x32_bf16(
                  af[i][kk], bfr[fn][kk], acc[i][fn], 0, 0, 0);
        __builtin_amdgcn_s_setprio(0);
        BAR();
      }
      // ---- phases q=1..3: A fm 2q,2q+1 (4 reads); stage B ----
#pragma unroll
      for (int qq = 1; qq < 4; ++qq) {
        short8 af[2][2];
#pragma unroll
        for (int i = 0; i < 2; ++i) {
          af[i][0] = *(const short8*)(Abase + (qq * 2 + i) * 2048 + cb0);
          af[i][1] = *(const short8*)(Abase + (qq * 2 + i) * 2048 + (cb0 ^ 64));
        }
        if (pf) {
          if (s == 0) {
            if (qq == 1) STAGE_B(t0 + 2, 0);
            if (qq == 2) STAGE_B(t0 + 2, 1);
          } else {
            if (qq == 1) STAGE_B(t0 + 3, 0);
            if (qq == 2) STAGE_B(t0 + 3, 1);
          }
        }
        BAR();
        __builtin_amdgcn_s_setprio(1);
#pragma unroll
        for (int i = 0; i < 2; ++i)
#pragma unroll
          for (int fn = 0; fn < 4; ++fn)
#pragma unroll
            for (int kk = 0; kk < 2; ++kk)
              acc[qq * 2 + i][fn] = __builtin_amdgcn_mfma_f32_16x16x32_bf16(
                  af[i][kk], bfr[fn][kk], acc[qq * 2 + i][fn], 0, 0, 0);
        __builtin_amdgcn_s_setprio(0);
        if (qq == 3) VMW(4);                 // phases 4 and 8 only, never 0
        BAR();
      }
    }
  }
#undef GLDS
#undef STAGE_A
#undef STAGE_B
#undef BAR
#undef VMW

  // epilogue: fn innermost -> full 64B lines per row
  float bv[4];
#pragma unroll
  for (int fn = 0; fn < 4; ++fn) bv[fn] = bias[n0 + (wn << 6) + (fn << 4) + llo];
#pragma unroll
  for (int fm = 0; fm < 8; ++fm) {
#pragma unroll
    for (int j = 0; j < 4; ++j) {
      const size_t row = (size_t)(m0 + (wm << 7) + (fm << 4) + (lhi << 2) + j);
#pragma unroll
      for (int fn = 0; fn < 4; ++fn) {
        const int col = n0 + (wn << 6) + (fn << 4) + llo;
        float v = acc[fm][fn][j] + bv[fn];
        if (RELU) v = fmaxf(v, 0.0f);
        if (OMODE == 2) {
          u16* P = (u16*)Cout;
          P[row * N + col] = f2bf(v + bf2f(P[row * N + col]));
        } else {
          ((u16*)Cout)[row * N + col] = f2bf(v);
        }
      }
    }
  }
}

// ------- final LayerNorm2: reads y bf16 (residual pre-added by GEMM2), writes f32 ---
__global__ __launch_bounds__(256) void ln2_kernel(
    float* __restrict__ out, const u16* __restrict__ y,
    const float* __restrict__ g2, const float* __restrict__ be2) {
  const int lane = threadIdx.x & 63;
  const int row = blockIdx.x * 4 + (threadIdx.x >> 6);
  const u16* yrow = y + ((size_t)row << 9);
  float* orow = out + ((size_t)row << 9);
  const int d0 = lane << 3;                  // 8 contiguous elems per lane
  short8 p = *(const short8*)(yrow + d0);
  float yv[8];
  float sum = 0.f, sum2 = 0.f;
#pragma unroll
  for (int m = 0; m < 8; ++m) {
    float v = bf2f((u16)p[m]);
    yv[m] = v; sum += v; sum2 += v * v;
  }
#pragma unroll
  for (int m = 1; m < 64; m <<= 1) {
    sum += __shfl_xor(sum, m, 64);
    sum2 += __shfl_xor(sum2, m, 64);
  }
  float mean = sum * (1.0f / 512.0f);
  float var = sum2 * (1.0f / 512.0f) - mean * mean;
  float scl = 1.0f / sqrtf(var + LN_EPS);
  f32x4 g0 = *(const f32x4*)(g2 + d0);
  f32x4 g1v = *(const f32x4*)(g2 + d0 + 4);
  f32x4 e0 = *(const f32x4*)(be2 + d0);
  f32x4 e1 = *(const f32x4*)(be2 + d0 + 4);
  f32x4 o0, o1;
#pragma unroll
  for (int m = 0; m < 4; ++m) o0[m] = (yv[m] - mean) * scl * g0[m] + e0[m];
#pragma unroll
  for (int m = 0; m < 4; ++m) o1[m] = (yv[m + 4] - mean) * scl * g1v[m] + e1[m];
  *(f32x4*)(orow + d0) = o0;
  *(f32x4*)(orow + d0 + 4) = o1;
}

// ---------------- launch ----------------
extern "C" void kernel_launch(void* const* d_in, const int* in_sizes, int n_in,
                              void* d_out, int out_size, void* d_ws, size_t ws_size,
                              hipStream_t stream) {
  const float* x   = (const float*)d_in[0];
  const float* W1  = (const float*)d_in[1];
  const float* b1  = (const float*)d_in[2];
  const float* W2  = (const float*)d_in[3];
  const float* b2  = (const float*)d_in[4];
  const float* g1  = (const float*)d_in[5];
  const float* be1 = (const float*)d_in[6];
  const float* g2  = (const float*)d_in[7];
  const float* be2 = (const float*)d_in[8];

  char* ws = (char*)d_ws;
  // layout: [0,32M) xt/Xre bf16 ; [32M,64M) Xim bf16 ; [0,128M) h (aliases, later)
  //         [128M,160M) proj bf16 (becomes y in-place via GEMM2)
  //         [160M,162M) W1T bf16 ; [162M,164M) W2T bf16
  u16* xt   = (u16*)(ws);
  u16* xim  = (u16*)(ws + (32u << 20));
  u16* proj = (u16*)(ws + (128u << 20));
  u16* w1t  = (u16*)(ws + (160u << 20));
  u16* w2t  = (u16*)(ws + (162u << 20));
  u16* h    = (u16*)(ws);                    // 128 MB, aliases xt+xim (dead by then)

  prep_w<<<1024, 256, 0, stream>>>(W1, w1t, 512, 2048);
  prep_w<<<1024, 256, 0, stream>>>(W2, w2t, 2048, 512);
  transpose_x<<<16384, 256, 0, stream>>>(x, xt);
  fft_s<<<1024, 512, 0, stream>>>(xt, xim);
  // Hermitian: 4 batches x 257 k-tiles (k in [0,4096]; mirrors written in-kernel)
  fft_d_ln<<<1028, 256, 0, stream>>>(xt, xim, x, g1, be1, proj);
  // GEMM1 (K=512): barrier-free A-resident kernel; grid 512 m-tiles x 8 n-tiles
  gemm_k512<<<4096, 256, 0, stream>>>(proj, w1t, b1, h, 2048);
  // GEMM2 (K=2048): 256^2 8-phase; epilogue adds residual + writes y bf16 IN PLACE on proj
  gemm256<false, 2, 2><<<256, 512, 0, stream>>>(h, w2t, b2, (void*)proj, 32768, 512, 2048);
  ln2_kernel<<<8192, 256, 0, stream>>>((float*)d_out, proj, g2, be2);
  (void)in_sizes; (void)n_in; (void)out_size; (void)ws_size;
}

// Round 11
// 265.137 us; speedup vs baseline: 1.2027x; 1.2027x over previous
//
#include <hip/hip_runtime.h>

typedef unsigned short u16;
typedef unsigned int u32;
typedef short short8 __attribute__((ext_vector_type(8)));
typedef float f32x4 __attribute__((ext_vector_type(4)));

#define LN_EPS 1e-3f
#define PI2 6.28318530717958647692f
#define AS1 __attribute__((address_space(1)))
#define AS3 __attribute__((address_space(3)))

__device__ __forceinline__ u16 f2bf(float f) {
  u32 u = __float_as_uint(f);
  u += 0x7fffu + ((u >> 16) & 1u);
  return (u16)(u >> 16);
}
__device__ __forceinline__ float bf2f(u16 h) {
  return __uint_as_float(((u32)h) << 16);
}

// ------- weight transpose + bf16: W[R][C] f32 -> Wt[C][R] bf16, 32x32 LDS tiles ----
__global__ __launch_bounds__(256) void prep_w(const float* __restrict__ W,
                                              u16* __restrict__ Wt, int R, int C) {
  __shared__ float tile[32][33];
  const int ct = C >> 5;
  int bc = blockIdx.x % ct;
  int br = blockIdx.x / ct;
  int tx = threadIdx.x & 31, ty = threadIdx.x >> 5;
  int r0 = br << 5, c0 = bc << 5;
#pragma unroll
  for (int i = 0; i < 32; i += 8)
    tile[ty + i][tx] = W[(size_t)(r0 + ty + i) * C + c0 + tx];
  __syncthreads();
#pragma unroll
  for (int i = 0; i < 32; i += 8)
    Wt[(size_t)(c0 + ty + i) * R + r0 + tx] = f2bf(tile[tx][ty + i]);
}

// ------- x[b][s][d] f32 -> xt[b][d][s] bf16 (tiled 32x32) ----------------
__global__ __launch_bounds__(256) void transpose_x(const float* __restrict__ x,
                                                   u16* __restrict__ xt) {
  __shared__ float tile[32][33];
  int blk = blockIdx.x;
  int b = blk >> 12;
  int rem = blk & 4095;
  int st = rem >> 4;   // s-tile 0..255
  int dt = rem & 15;   // d-tile 0..15
  int tx = threadIdx.x & 31, ty = threadIdx.x >> 5;
  int s0 = st << 5, d0 = dt << 5;
#pragma unroll
  for (int i = 0; i < 32; i += 8)
    tile[ty + i][tx] = x[(((size_t)(b << 13) + s0 + ty + i) << 9) + d0 + tx];
  __syncthreads();
#pragma unroll
  for (int i = 0; i < 32; i += 8)
    xt[(((size_t)(b << 9) + d0 + ty + i) << 13) + s0 + tx] = f2bf(tile[tx][ty + i]);
}

// ---------------- S-axis FFT (8192-pt DIF, register-blocked radix-16) --------------
// bf16 in / bf16 out (internals f32). Hermitian: only k in [0,4096] stored.
__device__ __constant__ float C16r[8] = {1.f, 0.92387953f, 0.70710678f, 0.38268343f,
                                         0.f, -0.38268343f, -0.70710678f, -0.92387953f};
__device__ __constant__ float C16i[8] = {0.f, -0.38268343f, -0.70710678f, -0.92387953f,
                                         -1.f, -0.92387953f, -0.70710678f, -0.38268343f};
__device__ __constant__ float C8r[4] = {1.f, 0.70710678f, 0.f, -0.70710678f};
__device__ __constant__ float C8i[4] = {0.f, -0.70710678f, -1.f, -0.70710678f};
__device__ __constant__ float C4r[2] = {1.f, 0.f};
__device__ __constant__ float C4i[2] = {0.f, -1.f};
__device__ __constant__ float C32r[16] = {
    1.f, 0.98078528f, 0.92387953f, 0.83146961f, 0.70710678f, 0.55557023f,
    0.38268343f, 0.19509032f, 0.f, -0.19509032f, -0.38268343f, -0.55557023f,
    -0.70710678f, -0.83146961f, -0.92387953f, -0.98078528f};
__device__ __constant__ float C32i[16] = {
    0.f, -0.19509032f, -0.38268343f, -0.55557023f, -0.70710678f, -0.83146961f,
    -0.92387953f, -0.98078528f, -1.f, -0.98078528f, -0.92387953f, -0.83146961f,
    -0.70710678f, -0.55557023f, -0.38268343f, -0.19509032f};
__device__ __constant__ int REV4[16] = {0, 8, 4, 12, 2, 10, 6, 14,
                                        1, 9, 5, 13, 3, 11, 7, 15};

__device__ __forceinline__ constexpr int rev4c(int v) {
  return ((v & 1) << 3) | ((v & 2) << 1) | ((v & 4) >> 1) | ((v & 8) >> 3);
}

#define BFLY(ar, ai, br, bi, wr, wi)                 \
  {                                                  \
    float dr_ = (ar) - (br), di_ = (ai) - (bi);      \
    (ar) += (br);                                    \
    (ai) += (bi);                                    \
    (br) = dr_ * (wr)-di_ * (wi);                    \
    (bi) = dr_ * (wi) + di_ * (wr);                  \
  }

__global__ __launch_bounds__(512) void fft_s(u16* __restrict__ X, u16* __restrict__ Xim) {
  __shared__ float zr[8448], zi[8448];      // padded: addr(i) = i + (i>>5)
  const int t = threadIdx.x;
  const int b = blockIdx.x >> 8;
  const int d0 = (blockIdx.x & 255) << 1;
  u16* r0 = X + (((size_t)(b << 9) + d0) << 13);
  u16* r1 = r0 + 8192;

  float xr[16], xi[16];
#pragma unroll
  for (int e = 0; e < 16; ++e) {            // coalesced loads, idx = t + 512e
    xr[e] = bf2f(r0[t + (e << 9)]);
    xi[e] = bf2f(r1[t + (e << 9)]);
  }

  // ---- pass A: strides 4096,2048,1024,512 in-register ----
  float c1, s1;
  sincosf(-PI2 * (float)t * (1.0f / 8192.0f), &s1, &c1);
  float c2 = c1 * c1 - s1 * s1, s2 = 2.f * c1 * s1;
  float c4 = c2 * c2 - s2 * s2, s4 = 2.f * c2 * s2;
  float c8 = c4 * c4 - s4 * s4, s8 = 2.f * c4 * s4;
#pragma unroll
  for (int e = 0; e < 8; ++e) {             // m=8192
    float wr = c1 * C16r[e] - s1 * C16i[e];
    float wi = c1 * C16i[e] + s1 * C16r[e];
    BFLY(xr[e], xi[e], xr[e + 8], xi[e + 8], wr, wi);
  }
#pragma unroll
  for (int e = 0; e < 16; ++e) {            // m=4096
    if ((e & 4) == 0) {
      int eb = e & 3;
      float wr = c2 * C8r[eb] - s2 * C8i[eb];
      float wi = c2 * C8i[eb] + s2 * C8r[eb];
      BFLY(xr[e], xi[e], xr[e + 4], xi[e + 4], wr, wi);
    }
  }
#pragma unroll
  for (int e = 0; e < 16; ++e) {            // m=2048
    if (((e >> 1) & 1) == 0) {
      int eb = e & 1;
      float wr = c4 * C4r[eb] - s4 * C4i[eb];
      float wi = c4 * C4i[eb] + s4 * C4r[eb];
      BFLY(xr[e], xi[e], xr[e + 2], xi[e + 2], wr, wi);
    }
  }
#pragma unroll
  for (int e = 0; e < 16; e += 2) {         // m=1024
    BFLY(xr[e], xi[e], xr[e + 1], xi[e + 1], c8, s8);
  }

  // ---- exchange A->B ----
#pragma unroll
  for (int e = 0; e < 16; ++e) {
    int idx = t + (e << 9);
    int a = idx + (idx >> 5);
    zr[a] = xr[e];
    zi[a] = xi[e];
  }
  __syncthreads();
  {
    const int f = t >> 5, l = t & 31;
#pragma unroll
    for (int e = 0; e < 16; ++e) {
      int idx = (f << 9) + (e << 5) + l;
      int a = idx + (idx >> 5);
      xr[e] = zr[a];
      xi[e] = zi[a];
    }
    // ---- pass B: strides 256,128,64,32 ----
    float bc1, bs1;
    sincosf(-PI2 * (float)l * (1.0f / 512.0f), &bs1, &bc1);
    float bc2 = bc1 * bc1 - bs1 * bs1, bs2 = 2.f * bc1 * bs1;
    float bc4 = bc2 * bc2 - bs2 * bs2, bs4 = 2.f * bc2 * bs2;
    float bc8 = bc4 * bc4 - bs4 * bs4, bs8 = 2.f * bc4 * bs4;
#pragma unroll
    for (int e = 0; e < 8; ++e) {           // m=512
      float wr = bc1 * C16r[e] - bs1 * C16i[e];
      float wi = bc1 * C16i[e] + bs1 * C16r[e];
      BFLY(xr[e], xi[e], xr[e + 8], xi[e + 8], wr, wi);
    }
#pragma unroll
    for (int e = 0; e < 16; ++e) {          // m=256
      if (((e >> 2) & 1) == 0) {
        int eb = e & 3;
        float wr = bc2 * C8r[eb] - bs2 * C8i[eb];
        float wi = bc2 * C8i[eb] + bs2 * C8r[eb];
        BFLY(xr[e], xi[e], xr[e + 4], xi[e + 4], wr, wi);
      }
    }
#pragma unroll
    for (int e = 0; e < 16; ++e) {          // m=128
      if (((e >> 1) & 1) == 0) {
        int eb = e & 1;
        float wr = bc4 * C4r[eb] - bs4 * C4i[eb];
        float wi = bc4 * C4i[eb] + bs4 * C4r[eb];
        BFLY(xr[e], xi[e], xr[e + 2], xi[e + 2], wr, wi);
      }
    }
#pragma unroll
    for (int e = 0; e < 16; e += 2) {       // m=64
      BFLY(xr[e], xi[e], xr[e + 1], xi[e + 1], bc8, bs8);
    }
    // ---- exchange B->C ----
    __syncthreads();
#pragma unroll
    for (int e = 0; e < 16; ++e) {
      int idx = (f << 9) + (e << 5) + l;
      int a = idx + (idx >> 5);
      zr[a] = xr[e];
      zi[a] = xi[e];
    }
  }
  __syncthreads();
#pragma unroll
  for (int j = 0; j < 16; ++j) {
    int idx = (t << 4) + j;
    int a = idx + (idx >> 5);
    xr[j] = zr[a];
    xi[j] = zi[a];
  }

  // ---- pass C: stride 16 via shfl, then 8,4,2,1 ----
  {
    const int odd = t & 1;
#pragma unroll
    for (int j = 0; j < 16; ++j) {          // m=32
      float pr = __shfl_xor(xr[j], 1);
      float pi = __shfl_xor(xi[j], 1);
      if (!odd) {
        xr[j] += pr;
        xi[j] += pi;
      } else {
        float dr = pr - xr[j], di = pi - xi[j];
        xr[j] = dr * C32r[j] - di * C32i[j];
        xi[j] = dr * C32i[j] + di * C32r[j];
      }
    }
#pragma unroll
    for (int j = 0; j < 8; ++j) {           // m=16
      BFLY(xr[j], xi[j], xr[j + 8], xi[j + 8], C16r[j], C16i[j]);
    }
#pragma unroll
    for (int j = 0; j < 16; ++j) {          // m=8
      if (((j >> 2) & 1) == 0) {
        BFLY(xr[j], xi[j], xr[j + 4], xi[j + 4], C8r[j & 3], C8i[j & 3]);
      }
    }
#pragma unroll
    for (int j = 0; j < 16; ++j) {          // m=4
      if (((j >> 1) & 1) == 0) {
        BFLY(xr[j], xi[j], xr[j + 2], xi[j + 2], C4r[j & 1], C4i[j & 1]);
      }
    }
#pragma unroll
    for (int j = 0; j < 16; j += 2) {       // m=2
      BFLY(xr[j], xi[j], xr[j + 1], xi[j + 1], 1.0f, 0.0f);
    }
  }

  // ---- bit-reversal scatter ----
  __syncthreads();
  {
    const int rt = __brev((u32)t) >> 23;    // 9-bit reverse
#pragma unroll
    for (int j = 0; j < 16; ++j) {
      int k = (REV4[j] << 9) | rt;
      int a = k + (k >> 5);
      zr[a] = xr[j];
      zi[a] = xi[j];
    }
  }
  __syncthreads();

  // ---- unpack two real FFTs; store only k in [0,4096] (Hermitian), bf16 ----
  u16* i0 = Xim + (((size_t)(b << 9) + d0) << 13);
  u16* i1 = i0 + 8192;
#pragma unroll
  for (int e = 0; e < 8; ++e) {
    int k = t + (e << 9);                   // 0..4095
    int nk = (8192 - k) & 8191;
    int ka = k + (k >> 5), na = nk + (nk >> 5);
    float zrk = zr[ka], zik = zi[ka], zrn = zr[na], zin = zi[na];
    r0[k] = f2bf(0.5f * (zrk + zrn));
    i0[k] = f2bf(0.5f * (zik - zin));
    r1[k] = f2bf(0.5f * (zik + zin));
    i1[k] = f2bf(0.5f * (zrn - zrk));
  }
  if (t == 0) {                             // k = 4096 (Nyquist, self-mirror)
    const int ka = 4096 + (4096 >> 5);
    r0[4096] = f2bf(zr[ka]);
    i0[4096] = 0;
    r1[4096] = f2bf(zi[ka]);
    i1[4096] = 0;
  }
}

// ------- D-axis FFT (512-pt, register-blocked) + residual + LN1, Hermitian dual ----
// bf16 spectral inputs; x residual f32. Grid: 4 batches x 257 k-tiles of 16 rows.
__global__ __launch_bounds__(256) void fft_d_ln(
    const u16* __restrict__ Xre, const u16* __restrict__ Xim,
    const float* __restrict__ x, const float* __restrict__ g1,
    const float* __restrict__ be1, u16* __restrict__ proj) {
  __shared__ float buf[16 * 528];           // 33792 B, one buffer for all phases
  const int tid = threadIdx.x;
  const int b = blockIdx.x / 257;
  const int kt = blockIdx.x - b * 257;
  const int s0 = kt << 4;                   // 0, 16, ..., 4096
  const int row = tid >> 4, t = tid & 15;   // compute roles
  const int so = tid & 15, dd = tid >> 4;   // staging roles

  float xr[32], xi[32];

#pragma unroll
  for (int it = 0; it < 32; ++it) {
    int d = dd + (it << 4);
    buf[so * 516 + d] = bf2f(Xre[(((size_t)(b << 9) + d) << 13) + s0 + so]);
  }
  __syncthreads();
#pragma unroll
  for (int e = 0; e < 32; ++e) xr[e] = buf[row * 516 + t + (e << 4)];
  __syncthreads();
#pragma unroll
  for (int it = 0; it < 32; ++it) {
    int d = dd + (it << 4);
    buf[so * 516 + d] = bf2f(Xim[(((size_t)(b << 9) + d) << 13) + s0 + so]);
  }
  __syncthreads();
#pragma unroll
  for (int e = 0; e < 32; ++e) xi[e] = buf[row * 516 + t + (e << 4)];
  __syncthreads();

  // ---- 5 DIF stages in-register (strides 256,128,64,32,16) ----
  float c1, s1;
  sincosf(-PI2 * (float)t * (1.0f / 512.0f), &s1, &c1);
  float c2 = c1 * c1 - s1 * s1, s2 = 2.f * c1 * s1;    // W256^t
  float c4 = c2 * c2 - s2 * s2, s4 = 2.f * c2 * s2;    // W128^t
  float c8 = c4 * c4 - s4 * s4, s8 = 2.f * c4 * s4;    // W64^t
  float c16 = c8 * c8 - s8 * s8, s16 = 2.f * c8 * s8;  // W32^t
#pragma unroll
  for (int e = 0; e < 16; ++e) {            // half=256
    float wr = c1 * C32r[e] - s1 * C32i[e];
    float wi = c1 * C32i[e] + s1 * C32r[e];
    BFLY(xr[e], xi[e], xr[e + 16], xi[e + 16], wr, wi);
  }
#pragma unroll
  for (int e = 0; e < 32; ++e) {            // half=128
    if ((e & 8) == 0) {
      int eb = e & 7;
      float wr = c2 * C16r[eb] - s2 * C16i[eb];
      float wi = c2 * C16i[eb] + s2 * C16r[eb];
      BFLY(xr[e], xi[e], xr[e + 8], xi[e + 8], wr, wi);
    }
  }
#pragma unroll
  for (int e = 0; e < 32; ++e) {            // half=64
    if ((e & 4) == 0) {
      int eb = e & 3;
      float wr = c4 * C8r[eb] - s4 * C8i[eb];
      float wi = c4 * C8i[eb] + s4 * C8r[eb];
      BFLY(xr[e], xi[e], xr[e + 4], xi[e + 4], wr, wi);
    }
  }
#pragma unroll
  for (int e = 0; e < 32; ++e) {            // half=32
    if ((e & 2) == 0) {
      int eb = e & 1;
      float wr = c8 * C4r[eb] - s8 * C4i[eb];
      float wi = c8 * C4i[eb] + s8 * C4r[eb];
      BFLY(xr[e], xi[e], xr[e + 2], xi[e + 2], wr, wi);
    }
  }
#pragma unroll
  for (int e = 0; e < 32; e += 2) {         // half=16
    BFLY(xr[e], xi[e], xr[e + 1], xi[e + 1], c16, s16);
  }

  // ---- exchange ----
#pragma unroll
  for (int e = 0; e < 32; ++e) {
    int p = (e << 4) + t;
    buf[row * 528 + p + (p >> 5)] = xr[e];
  }
  __syncthreads();
#pragma unroll
  for (int j = 0; j < 32; ++j) xr[j] = buf[row * 528 + 33 * t + j];
  __syncthreads();
#pragma unroll
  for (int e = 0; e < 32; ++e) {
    int p = (e << 4) + t;
    buf[row * 528 + p + (p >> 5)] = xi[e];
  }
  __syncthreads();
#pragma unroll
  for (int j = 0; j < 32; ++j) xi[j] = buf[row * 528 + 33 * t + j];
  __syncthreads();

  // ---- two 16-pt DIF FFTs in-register ----
#pragma unroll
  for (int o = 0; o < 32; o += 16) {
#pragma unroll
    for (int j = 0; j < 8; ++j)             // half=8
      BFLY(xr[o + j], xi[o + j], xr[o + j + 8], xi[o + j + 8], C16r[j], C16i[j]);
#pragma unroll
    for (int j = 0; j < 16; ++j)            // half=4
      if ((j & 4) == 0)
        BFLY(xr[o + j], xi[o + j], xr[o + j + 4], xi[o + j + 4], C8r[j & 3], C8i[j & 3]);
#pragma unroll
    for (int j = 0; j < 16; ++j)            // half=2
      if ((j & 2) == 0)
        BFLY(xr[o + j], xi[o + j], xr[o + j + 2], xi[o + j + 2], C4r[j & 1], C4i[j & 1]);
#pragma unroll
    for (int j = 0; j < 16; j += 2)         // half=1
      BFLY(xr[o + j], xi[o + j], xr[o + j + 1], xi[o + j + 1], 1.0f, 0.0f);
  }

  // ---- scatter Re at bit-reversed k ----
  {
    const int rt4 = __brev((u32)t) >> 28;
#pragma unroll
    for (int j = 0; j < 16; ++j) {
      const int rj = rev4c(j);
      buf[row * 528 + 33 * rj + rt4] = xr[j];
      buf[row * 528 + 33 * rj + 16 + rt4] = xr[16 + j];
    }
  }
  __syncthreads();

  const int k = s0 + row;
  // ---- main row k: residual add + LN over D=512, write if k <= 4096 ----
  {
    const float* xrow = x + (((size_t)(b << 13) + k) << 9);
    float v[32];
    float sum = 0.f, sum2 = 0.f;
#pragma unroll
    for (int m = 0; m < 32; ++m) {
      int d = t + (m << 4);
      float val = buf[row * 528 + d + (d >> 5)] + xrow[d];
      v[m] = val;
      sum += val;
      sum2 += val * val;
    }
#pragma unroll
    for (int m = 1; m < 16; m <<= 1) {
      sum += __shfl_xor(sum, m, 16);
      sum2 += __shfl_xor(sum2, m, 16);
    }
    float mean = sum * (1.0f / 512.0f);
    float var = sum2 * (1.0f / 512.0f) - mean * mean;
    float scl = 1.0f / sqrtf(var + LN_EPS);
    if (k <= 4096) {
      u16* prow = proj + (((size_t)(b << 13) + k) << 9);
#pragma unroll
      for (int m = 0; m < 32; ++m) {
        int d = t + (m << 4);
        prow[d] = f2bf((v[m] - mean) * scl * g1[d] + be1[d]);
      }
    }
  }
  // ---- mirror row 8192-k: Re[d] = buf_re[(512-d)&511], for k in [1,4095] ----
  if (k >= 1 && k <= 4095) {
    const int sm = 8192 - k;
    const float* xrow = x + (((size_t)(b << 13) + sm) << 9);
    float v[32];
    float sum = 0.f, sum2 = 0.f;
#pragma unroll
    for (int m = 0; m < 32; ++m) {
      int d = t + (m << 4);
      int dm = (512 - d) & 511;
      float val = buf[row * 528 + dm + (dm >> 5)] + xrow[d];
      v[m] = val;
      sum += val;
      sum2 += val * val;
    }
#pragma unroll
    for (int m = 1; m < 16; m <<= 1) {
      sum += __shfl_xor(sum, m, 16);
      sum2 += __shfl_xor(sum2, m, 16);
    }
    float mean = sum * (1.0f / 512.0f);
    float var = sum2 * (1.0f / 512.0f) - mean * mean;
    float scl = 1.0f / sqrtf(var + LN_EPS);
    u16* prow = proj + (((size_t)(b << 13) + sm) << 9);
#pragma unroll
    for (int m = 0; m < 32; ++m) {
      int d = t + (m << 4);
      prow[d] = f2bf((v[m] - mean) * scl * g1[d] + be1[d]);
    }
  }
}

// ------- GEMM 128x128 (m97 structure), for short-K GEMM1: K=512 --------------------
template <bool RELU, bool OUT_BF16, int GH>
__global__ __launch_bounds__(256, 2) void gemm_bt(
    const u16* __restrict__ A, const u16* __restrict__ Bt,
    const float* __restrict__ bias, void* __restrict__ Cout,
    int M, int N, int K) {
  const int tid = threadIdx.x;
  const int lane = tid & 63;
  const int wave = tid >> 6;
  const int wm = wave >> 1, wn = wave & 1;
  const int llo = lane & 15, lhi = lane >> 4;

  const int nwg = gridDim.x;                 // divisible by 8 and by GH*NT
  const int q = nwg >> 3;
  const int b2 = ((int)blockIdx.x & 7) * q + ((int)blockIdx.x >> 3);  // XCD chunk
  const int NT = N >> 7;
  const int GSZ = GH * NT;
  const int grp = b2 / GSZ;
  const int r = b2 - grp * GSZ;
  const int tn = r / GH;
  const int tm = grp * GH + (r - tn * GH);
  const int m0 = tm << 7, n0 = tn << 7;

  __shared__ short8 smem[2048];              // 32 KB: A tile 16K + B tile 16K
  char* ldsA = (char*)&smem[0];
  char* ldsB = ldsA + 16384;

  f32x4 acc[4][4] = {};

  const int trow = tid >> 3;                                  // staging row 0..31
  const int ksw = (((tid & 7) ^ (trow & 7)) << 3);            // inverse-swizzled source k
  const int wbase = wave << 10;                               // wave-uniform LDS base
  const int swz = (llo & 7) << 4;                             // read-side XOR

  const int KT = K >> 6;
  for (int kt = 0; kt < KT; ++kt) {
    const int k0 = (kt << 6) + ksw;
    __syncthreads();
#pragma unroll
    for (int r4 = 0; r4 < 4; ++r4) {
      const int grow = (r4 << 5) + trow;
      const u16* ga = A + (size_t)(m0 + grow) * K + k0;
      const u16* gb = Bt + (size_t)(n0 + grow) * K + k0;
      __builtin_amdgcn_global_load_lds((const AS1 void*)ga,
                                       (AS3 void*)(ldsA + (r4 << 12) + wbase), 16, 0, 0);
      __builtin_amdgcn_global_load_lds((const AS1 void*)gb,
                                       (AS3 void*)(ldsB + (r4 << 12) + wbase), 16, 0, 0);
    }
    __syncthreads();
#pragma unroll
    for (int kk = 0; kk < 2; ++kk) {
      const int cbx = ((kk << 6) | (lhi << 4)) ^ swz;
      short8 af[4], bfr[4];
#pragma unroll
      for (int mt = 0; mt < 4; ++mt)
        af[mt] = *(const short8*)(ldsA + (((wm << 6) + (mt << 4) + llo) << 7) + cbx);
#pragma unroll
      for (int nt = 0; nt < 4; ++nt)
        bfr[nt] = *(const short8*)(ldsB + (((wn << 6) + (nt << 4) + llo) << 7) + cbx);
#pragma unroll
      for (int mt = 0; mt < 4; ++mt)
#pragma unroll
        for (int nt = 0; nt < 4; ++nt)
          acc[mt][nt] =
              __builtin_amdgcn_mfma_f32_16x16x32_bf16(af[mt], bfr[nt], acc[mt][nt], 0, 0, 0);
    }
  }
  // epilogue: nt innermost -> each lane-row's 4 fragments form a 128B run per wave
  float bv[4];
#pragma unroll
  for (int nt = 0; nt < 4; ++nt) bv[nt] = bias[n0 + (wn << 6) + (nt << 4) + llo];
#pragma unroll
  for (int mt = 0; mt < 4; ++mt) {
    const int rbase = m0 + (wm << 6) + (mt << 4) + (lhi << 2);
#pragma unroll
    for (int j = 0; j < 4; ++j) {
#pragma unroll
      for (int nt = 0; nt < 4; ++nt) {
        const int col = n0 + (wn << 6) + (nt << 4) + llo;
        float v = acc[mt][nt][j] + bv[nt];
        if (RELU) v = fmaxf(v, 0.0f);
        if (OUT_BF16) ((u16*)Cout)[(size_t)(rbase + j) * N + col] = f2bf(v);
        else          ((float*)Cout)[(size_t)(rbase + j) * N + col] = v;
      }
    }
  }
}

// ---------------- GEMM 256x256, BK=64, 8 waves, 8-phase counted-vmcnt pipeline -----
// OMODE: 1 = bf16 store; 2 = residual RMW in-place on bf16 Cout (y = C + acc + bias)
template <bool RELU, int OMODE, int GH>
__global__ __launch_bounds__(512, 2) void gemm256(
    const u16* __restrict__ A, const u16* __restrict__ Bt,
    const float* __restrict__ bias, void* __restrict__ Cout,
    int M, int N, int K) {
  const int tid = threadIdx.x;
  const int lane = tid & 63;
  const int wave = tid >> 6;                 // 0..7
  const int wm = wave >> 2;                  // 0..1 (M half)
  const int wn = wave & 3;                   // 0..3 (N quarter)
  const int llo = lane & 15, lhi = lane >> 4;

  const int nwg = gridDim.x;                 // % 8 == 0 and % (GH*NT) == 0
  const int q = nwg >> 3;
  const int b2 = ((int)blockIdx.x & 7) * q + ((int)blockIdx.x >> 3);  // XCD chunk
  const int NT = N >> 8;
  const int GSZ = GH * NT;
  const int grp = b2 / GSZ;
  const int rr = b2 - grp * GSZ;
  const int tn = rr / GH;
  const int tm = grp * GH + (rr - tn * GH);
  const int m0 = tm << 8, n0 = tn << 8;

  __shared__ short8 smem[8192];              // 128 KB
  char* ldsA = (char*)&smem[0];              // [slot<<15][half<<14][row*128]
  char* ldsB = ldsA + 65536;

  f32x4 acc[8][4] = {};

  const int trow = tid >> 3;                                   // 0..63
  const int ksw = ((tid & 7) ^ (trow & 7)) << 3;               // presw src k (elems)
  const int swz = (llo & 7) << 4;                              // read-side XOR
  const int cb0 = (lhi << 4) ^ swz;                            // kk=0 col; kk=1: ^64
  const char* Ab0 = ldsA + wm * 16384 + llo * 128;
  const char* Bb0 = ldsB + (wn >> 1) * 16384 + (((wn & 1) << 6) + llo) * 128;

#define GLDS(g_, d_) __builtin_amdgcn_global_load_lds((const AS1 void*)(g_), (AS3 void*)(d_), 16, 0, 0)
#define STAGE_A(kt, hf) {                                                        \
    const u16* g_ = A + (size_t)(m0 + ((hf) << 7) + trow) * K + ((kt) << 6) + ksw; \
    char* d_ = ldsA + (((kt)&1) << 15) + ((hf) << 14) + tid * 16;                \
    GLDS(g_, d_); GLDS(g_ + ((size_t)64) * K, d_ + 8192); }
#define STAGE_B(kt, hf) {                                                        \
    const u16* g_ = Bt + (size_t)(n0 + ((hf) << 7) + trow) * K + ((kt) << 6) + ksw; \
    char* d_ = ldsB + (((kt)&1) << 15) + ((hf) << 14) + tid * 16;                \
    GLDS(g_, d_); GLDS(g_ + ((size_t)64) * K, d_ + 8192); }
#define BAR() { __builtin_amdgcn_sched_barrier(0); __builtin_amdgcn_s_barrier(); \
                __builtin_amdgcn_sched_barrier(0); }
#define VMW(n_) { asm volatile("s_waitcnt vmcnt(" #n_ ")" ::: "memory"); }

  const int KT = K >> 6;
  // prologue: slot0 <- kt0 (A+B), B slot1 <- kt1; A slot1 staged at P1 of iter 0
  STAGE_A(0, 0); STAGE_A(0, 1); STAGE_B(0, 0); STAGE_B(0, 1);
  STAGE_B(1, 0); STAGE_B(1, 1);
  VMW(0);
  BAR();

  for (int t0 = 0; t0 < KT; t0 += 2) {
    const bool pf = (t0 + 2 < KT);
#pragma unroll
    for (int s = 0; s < 2; ++s) {            // s=0: phases 1-4 (kt=t0); s=1: 5-8
      const char* Abase = Ab0 + (s << 15);
      const char* Bbase = Bb0 + (s << 15);
      short8 bfr[4][2];
      // ---- phase q=0: B full (8) + A fm0,1 (4); stage A of other slot ----
      {
#pragma unroll
        for (int fn = 0; fn < 4; ++fn) {
          bfr[fn][0] = *(const short8*)(Bbase + fn * 2048 + cb0);
          bfr[fn][1] = *(const short8*)(Bbase + fn * 2048 + (cb0 ^ 64));
        }
        short8 af[2][2];
#pragma unroll
        for (int i = 0; i < 2; ++i) {
          af[i][0] = *(const short8*)(Abase + i * 2048 + cb0);
          af[i][1] = *(const short8*)(Abase + i * 2048 + (cb0 ^ 64));
        }
        if (s == 0) {
          STAGE_A(t0 + 1, 0); STAGE_A(t0 + 1, 1);
        } else if (pf) {
          STAGE_A(t0 + 2, 0); STAGE_A(t0 + 2, 1);
        }
        BAR();
        __builtin_amdgcn_s_setprio(1);
#pragma unroll
        for (int i = 0; i < 2; ++i)
#pragma unroll
          for (int fn = 0; fn < 4; ++fn)
#pragma unroll
            for (int kk = 0; kk < 2; ++kk)
              acc[i][fn] = __builtin_amdgcn_mfma_f32_16x16x32_bf16(
                  af[i][kk], bfr[fn][kk], acc[i][fn], 0, 0, 0);
        __builtin_amdgcn_s_setprio(0);
        BAR();
      }
      // ---- phases q=1..3: A fm 2q,2q+1 (4 reads); stage B ----
#pragma unroll
      for (int qq = 1; qq < 4; ++qq) {
        short8 af[2][2];
#pragma unroll
        for (int i = 0; i < 2; ++i) {
          af[i][0] = *(const short8*)(Abase + (qq * 2 + i) * 2048 + cb0);
          af[i][1] = *(const short8*)(Abase + (qq * 2 + i) * 2048 + (cb0 ^ 64));
        }
        if (pf) {
          if (s == 0) {
            if (qq == 1) STAGE_B(t0 + 2, 0);
            if (qq == 2) STAGE_B(t0 + 2, 1);
          } else {
            if (qq == 1) STAGE_B(t0 + 3, 0);
            if (qq == 2) STAGE_B(t0 + 3, 1);
          }
        }
        BAR();
        __builtin_amdgcn_s_setprio(1);
#pragma unroll
        for (int i = 0; i < 2; ++i)
#pragma unroll
          for (int fn = 0; fn < 4; ++fn)
#pragma unroll
            for (int kk = 0; kk < 2; ++kk)
              acc[qq * 2 + i][fn] = __builtin_amdgcn_mfma_f32_16x16x32_bf16(
                  af[i][kk], bfr[fn][kk], acc[qq * 2 + i][fn], 0, 0, 0);
        __builtin_amdgcn_s_setprio(0);
        if (qq == 3) VMW(4);                 // phases 4 and 8 only, never 0
        BAR();
      }
    }
  }
#undef GLDS
#undef STAGE_A
#undef STAGE_B
#undef BAR
#undef VMW

  // epilogue: fn innermost -> full 64B lines per row
  float bv[4];
#pragma unroll
  for (int fn = 0; fn < 4; ++fn) bv[fn] = bias[n0 + (wn << 6) + (fn << 4) + llo];
#pragma unroll
  for (int fm = 0; fm < 8; ++fm) {
#pragma unroll
    for (int j = 0; j < 4; ++j) {
      const size_t row = (size_t)(m0 + (wm << 7) + (fm << 4) + (lhi << 2) + j);
#pragma unroll
      for (int fn = 0; fn < 4; ++fn) {
        const int col = n0 + (wn << 6) + (fn << 4) + llo;
        float v = acc[fm][fn][j] + bv[fn];
        if (RELU) v = fmaxf(v, 0.0f);
        if (OMODE == 2) {
          u16* P = (u16*)Cout;
          P[row * N + col] = f2bf(v + bf2f(P[row * N + col]));
        } else {
          ((u16*)Cout)[row * N + col] = f2bf(v);
        }
      }
    }
  }
}

// ------- final LayerNorm2: reads y bf16 (residual pre-added by GEMM2), writes f32 ---
__global__ __launch_bounds__(256) void ln2_kernel(
    float* __restrict__ out, const u16* __restrict__ y,
    const float* __restrict__ g2, const float* __restrict__ be2) {
  const int lane = threadIdx.x & 63;
  const int row = blockIdx.x * 4 + (threadIdx.x >> 6);
  const u16* yrow = y + ((size_t)row << 9);
  float* orow = out + ((size_t)row << 9);
  const int d0 = lane << 3;                  // 8 contiguous elems per lane
  short8 p = *(const short8*)(yrow + d0);
  float yv[8];
  float sum = 0.f, sum2 = 0.f;
#pragma unroll
  for (int m = 0; m < 8; ++m) {
    float v = bf2f((u16)p[m]);
    yv[m] = v; sum += v; sum2 += v * v;
  }
#pragma unroll
  for (int m = 1; m < 64; m <<= 1) {
    sum += __shfl_xor(sum, m, 64);
    sum2 += __shfl_xor(sum2, m, 64);
  }
  float mean = sum * (1.0f / 512.0f);
  float var = sum2 * (1.0f / 512.0f) - mean * mean;
  float scl = 1.0f / sqrtf(var + LN_EPS);
  f32x4 g0 = *(const f32x4*)(g2 + d0);
  f32x4 g1v = *(const f32x4*)(g2 + d0 + 4);
  f32x4 e0 = *(const f32x4*)(be2 + d0);
  f32x4 e1 = *(const f32x4*)(be2 + d0 + 4);
  f32x4 o0, o1;
#pragma unroll
  for (int m = 0; m < 4; ++m) o0[m] = (yv[m] - mean) * scl * g0[m] + e0[m];
#pragma unroll
  for (int m = 0; m < 4; ++m) o1[m] = (yv[m + 4] - mean) * scl * g1v[m] + e1[m];
  *(f32x4*)(orow + d0) = o0;
  *(f32x4*)(orow + d0 + 4) = o1;
}

// ---------------- launch ----------------
extern "C" void kernel_launch(void* const* d_in, const int* in_sizes, int n_in,
                              void* d_out, int out_size, void* d_ws, size_t ws_size,
                              hipStream_t stream) {
  const float* x   = (const float*)d_in[0];
  const float* W1  = (const float*)d_in[1];
  const float* b1  = (const float*)d_in[2];
  const float* W2  = (const float*)d_in[3];
  const float* b2  = (const float*)d_in[4];
  const float* g1  = (const float*)d_in[5];
  const float* be1 = (const float*)d_in[6];
  const float* g2  = (const float*)d_in[7];
  const float* be2 = (const float*)d_in[8];

  char* ws = (char*)d_ws;
  // layout: [0,32M) xt/Xre bf16 ; [32M,64M) Xim bf16 ; [0,128M) h (aliases, later)
  //         [128M,160M) proj bf16 (becomes y in-place via GEMM2)
  //         [160M,162M) W1T bf16 ; [162M,164M) W2T bf16
  u16* xt   = (u16*)(ws);
  u16* xim  = (u16*)(ws + (32u << 20));
  u16* proj = (u16*)(ws + (128u << 20));
  u16* w1t  = (u16*)(ws + (160u << 20));
  u16* w2t  = (u16*)(ws + (162u << 20));
  u16* h    = (u16*)(ws);                    // 128 MB, aliases xt+xim (dead by then)

  prep_w<<<1024, 256, 0, stream>>>(W1, w1t, 512, 2048);
  prep_w<<<1024, 256, 0, stream>>>(W2, w2t, 2048, 512);
  transpose_x<<<16384, 256, 0, stream>>>(x, xt);
  fft_s<<<1024, 512, 0, stream>>>(xt, xim);
  // Hermitian: 4 batches x 257 k-tiles (k in [0,4096]; mirrors written in-kernel)
  fft_d_ln<<<1028, 256, 0, stream>>>(xt, xim, x, g1, be1, proj);
  // GEMM1 (K=512, short): m97-128^2 structure, GH=8 L2 grouping
  gemm_bt<true, true, 8><<<4096, 256, 0, stream>>>(proj, w1t, b1, (void*)h, 32768, 2048, 512);
  // GEMM2 (K=2048): 256^2 8-phase; epilogue adds residual + writes y bf16 IN PLACE on proj
  gemm256<false, 2, 2><<<256, 512, 0, stream>>>(h, w2t, b2, (void*)proj, 32768, 512, 2048);
  ln2_kernel<<<8192, 256, 0, stream>>>((float*)d_out, proj, g2, be2);
  (void)in_sizes; (void)n_in; (void)out_size; (void)ws_size;
}